// Round 15
// baseline (188.102 us; speedup 1.0000x reference)
//
#include <hip/hip_runtime.h>
#include <math.h>

// MultiHeadAttentionMemory: B=256, F=4096, M=4096 memories.
// seq_len==1 => attention==identity => o = (z@Wv+bv)@Wo+bo  (Wq/Wk dead).
// Split-bf16 (bf16x3: ah*bh + ah*bl + al*bh) MFMA for the 3 precision-
// sensitive GEMMs; plain bf16 MFMA for z_hat = w@mem.
// R15 = R10 (best: packed-A, coalesced B, BM=256, grid (32,1,8)) with
// BK=64 phases: each LDS buffer holds 2 K-tiles, ONE barrier per 2 tiles
// (halves all-wave drain points), 48 MFMA + 16 staged loads per interval.
#define MB 256
#define FF 4096

typedef __attribute__((ext_vector_type(8))) short short8v;
typedef __attribute__((ext_vector_type(4))) short short4v;
typedef __attribute__((ext_vector_type(16))) float f32x16;

__device__ __forceinline__ unsigned short bf16_rne(float f) {
    unsigned u = __builtin_bit_cast(unsigned, f);
    u += 0x7fffu + ((u >> 16) & 1u);
    return (unsigned short)(u >> 16);
}
__device__ __forceinline__ float bf16_f(unsigned short h) {
    unsigned u = ((unsigned)h) << 16;
    return __builtin_bit_cast(float, u);
}
// packed-A element index (in shorts); m in [0,256), k in [0,4096)
__device__ __forceinline__ size_t apack_idx(int m, int k) {
    return ((size_t)(m >> 5) << 17) + ((size_t)(k >> 3) << 8)
         + ((m & 31) << 3) + (k & 7);
}

// ---------------- reductions ----------------
__device__ __forceinline__ float block_reduce_sum(float v, float* red) {
    const int tid = threadIdx.x;
    red[tid] = v; __syncthreads();
    for (int s = 128; s > 0; s >>= 1) {
        if (tid < s) red[tid] += red[tid + s];
        __syncthreads();
    }
    float r = red[0]; __syncthreads();
    return r;
}
__device__ __forceinline__ float block_reduce_max(float v, float* red) {
    const int tid = threadIdx.x;
    red[tid] = v; __syncthreads();
    for (int s = 128; s > 0; s >>= 1) {
        if (tid < s) red[tid] = fmaxf(red[tid], red[tid + s]);
        __syncthreads();
    }
    float r = red[0]; __syncthreads();
    return r;
}

// dst[row] = max(||src[row,:]||, 1e-8)
__global__ __launch_bounds__(256) void rownorm_kernel(
    const float* __restrict__ src, float* __restrict__ dst, int ncols)
{
    __shared__ float red[256];
    const int row = blockIdx.x, tid = threadIdx.x;
    const float4* p = (const float4*)(src + (size_t)row * ncols);
    float s = 0.f;
    for (int i = tid; i < ncols / 4; i += 256) {
        float4 v = p[i];
        s += v.x * v.x + v.y * v.y + v.z * v.z + v.w * v.w;
    }
    float tot = block_reduce_sum(s, red);
    if (tid == 0) dst[row] = fmaxf(sqrtf(tot), 1e-8f);
}

// ---------------- fp32 -> bf16 hi/lo split, PACKED output ----------------
__global__ __launch_bounds__(256) void split_plain(
    const float* __restrict__ src, unsigned short* __restrict__ hi,
    unsigned short* __restrict__ lo)
{
    const size_t i4 = (size_t)blockIdx.x * 256 + threadIdx.x;
    const size_t base = i4 * 4;
    const int m = (int)(base >> 12), k = (int)(base & 4095);
    const float4 v = *(const float4*)(src + base);
    unsigned short h0 = bf16_rne(v.x), h1 = bf16_rne(v.y), h2 = bf16_rne(v.z), h3 = bf16_rne(v.w);
    const size_t po = apack_idx(m, k);   // k aligned to 4 -> 4 contiguous shorts
    short4v hv = { (short)h0, (short)h1, (short)h2, (short)h3 };
    *(short4v*)(hi + po) = hv;
    short4v lv = { (short)bf16_rne(v.x - bf16_f(h0)), (short)bf16_rne(v.y - bf16_f(h1)),
                   (short)bf16_rne(v.z - bf16_f(h2)), (short)bf16_rne(v.w - bf16_f(h3)) };
    *(short4v*)(lo + po) = lv;
}

// ---------------- MFMA GEMM, split-K, BK=64 phases ----------------
// C[256][4096](->part) = A[256][4096] @ B, BM=256, BN=128, BK=32 tiles
// staged in PAIRS (64 k per barrier interval). K-chunk 512 (16 tiles, 8
// intervals). Block = 512 threads = 8 waves (4m x 2n), wave tile 64x64.
// grid (32, 1, 8) = 256 blocks.
// A: PACKED bf16 planes, register-direct, coalesced frag loads, 1-ahead.
// BSRC 0: B raw fp32 [k][n] (weights; zhat's mem) - coalesced scalar loads.
// BSRC 1: B raw fp32 [n][k] (logits' mem rows) - 32B/lane contiguous loads.
// B split/rounded in-VALU -> blocked LDS granule (k8*128+n)*16B per plane.
// LDS buffer = 2 tiles x PLANES x 8KB; ONE __syncthreads per 2 tiles.
template <int BSRC, int SPLIT>
__global__ __launch_bounds__(512, 2) void gemm_sk(
    const unsigned short* __restrict__ Ah, const unsigned short* __restrict__ Al,
    const float* __restrict__ B, float* __restrict__ part)
{
    constexpr int PLANES = SPLIT ? 2 : 1;
    constexpr int TILEBYTES = PLANES * 8192;       // one tile (hi+lo planes)
    constexpr int BUFBYTES = 2 * TILEBYTES;        // buffer = 2 tiles
    __shared__ char Bs[2 * BUFBYTES];

    const int tid = threadIdx.x;
    const int lane = tid & 63, w = tid >> 6;
    const int wm = w >> 1, wn = w & 1;
    const int bn0 = blockIdx.x * 128;
    const int k0 = blockIdx.z * 512;
    const int l31 = lane & 31;

    // ---- staging source + LDS granule slot
    const float* bsrc;
    int gslot;
    if constexpr (BSRC == 0) {
        const int tk8 = tid >> 7, tn = tid & 127;       // k8 0..3, n 0..127
        bsrc = B + (size_t)(k0 + tk8 * 8) * FF + bn0 + tn;
        gslot = tid;                                     // = tk8*128 + tn
    } else {
        const int tn = tid >> 2, tk8 = tid & 3;          // n 0..127, k8 0..3
        bsrc = B + (size_t)(bn0 + tn) * FF + k0 + tk8 * 8;
        gslot = tk8 * 128 + tn;
    }

    float rB0, rB1, rB2, rB3, rB4, rB5, rB6, rB7;
    float sB0, sB1, sB2, sB3, sB4, sB5, sB6, sB7;

#define LOADB(S, T_)                                                          \
    {                                                                         \
        if constexpr (BSRC == 0) {                                            \
            const float* p_ = bsrc + (size_t)(T_) * 32 * FF;                  \
            S##B0 = p_[0 * FF]; S##B1 = p_[1 * FF];                           \
            S##B2 = p_[2 * FF]; S##B3 = p_[3 * FF];                           \
            S##B4 = p_[4 * FF]; S##B5 = p_[5 * FF];                           \
            S##B6 = p_[6 * FF]; S##B7 = p_[7 * FF];                           \
        } else {                                                              \
            const float* p_ = bsrc + (T_) * 32;                               \
            const float4 f0_ = *(const float4*)p_;                            \
            const float4 f1_ = *(const float4*)(p_ + 4);                      \
            S##B0 = f0_.x; S##B1 = f0_.y; S##B2 = f0_.z; S##B3 = f0_.w;       \
            S##B4 = f1_.x; S##B5 = f1_.y; S##B6 = f1_.z; S##B7 = f1_.w;       \
        }                                                                     \
    }

#define WRITEB(S, BUF_, TS_)                                                  \
    {                                                                         \
        unsigned short h0_ = bf16_rne(S##B0), h1_ = bf16_rne(S##B1),          \
                       h2_ = bf16_rne(S##B2), h3_ = bf16_rne(S##B3),          \
                       h4_ = bf16_rne(S##B4), h5_ = bf16_rne(S##B5),          \
                       h6_ = bf16_rne(S##B6), h7_ = bf16_rne(S##B7);          \
        short8v hv_ = { (short)h0_, (short)h1_, (short)h2_, (short)h3_,       \
                        (short)h4_, (short)h5_, (short)h6_, (short)h7_ };     \
        char* d_ = Bs + (BUF_) * BUFBYTES + (TS_) * TILEBYTES + gslot * 16;   \
        *(short8v*)d_ = hv_;                                                  \
        if constexpr (SPLIT) {                                                \
            short8v lv_ = { (short)bf16_rne(S##B0 - bf16_f(h0_)),             \
                            (short)bf16_rne(S##B1 - bf16_f(h1_)),             \
                            (short)bf16_rne(S##B2 - bf16_f(h2_)),             \
                            (short)bf16_rne(S##B3 - bf16_f(h3_)),             \
                            (short)bf16_rne(S##B4 - bf16_f(h4_)),             \
                            (short)bf16_rne(S##B5 - bf16_f(h5_)),             \
                            (short)bf16_rne(S##B6 - bf16_f(h6_)),             \
                            (short)bf16_rne(S##B7 - bf16_f(h7_)) };           \
            *(short8v*)(d_ + 8192) = lv_;                                     \
        }                                                                     \
    }

    // ---- B fragment reads: byte = ((KH*2+(lane>>5))*128 + wn*64 + ns*32 + l31)*16
    const char* const fragbase =
        (const char*)Bs + (((lane >> 5) * 128) + wn * 64 + l31) * 16;
#define BFRAG(BUF_, TS_, P_, KH_, NS_)                                        \
    (*(const short8v*)(fragbase + (BUF_) * BUFBYTES + (TS_) * TILEBYTES +     \
                       (P_) * 8192 + (KH_) * 4096 + (NS_) * 512))

    // ---- A pointers (packed planes, coalesced): wave rows wm*64 .. +63
    const size_t abase = ((size_t)(wm * 2) << 17) + ((size_t)blockIdx.z << 14)
                       + ((lane >> 5) << 8) + (l31 << 3);
    const unsigned short* pAh = Ah + abase;
    const unsigned short* pAl = SPLIT ? (Al + abase) : pAh;

    short8v cA_0h0, cA_0h1, cA_1h0, cA_1h1, cA_0l0, cA_0l1, cA_1l0, cA_1l1;
    short8v nA_0h0, nA_0h1, nA_1h0, nA_1h1, nA_0l0, nA_0l1, nA_1l0, nA_1l1;

    // A frag offsets (shorts): subtile*131072 + t*1024 + kh*512
#define LOADA(SET, T_)                                                        \
    {                                                                         \
        const int o_ = (T_) * 1024;                                           \
        SET##_0h0 = *(const short8v*)(pAh + o_);                              \
        SET##_0h1 = *(const short8v*)(pAh + o_ + 512);                        \
        SET##_1h0 = *(const short8v*)(pAh + 131072 + o_);                     \
        SET##_1h1 = *(const short8v*)(pAh + 131072 + o_ + 512);               \
        if constexpr (SPLIT) {                                                \
            SET##_0l0 = *(const short8v*)(pAl + o_);                          \
            SET##_0l1 = *(const short8v*)(pAl + o_ + 512);                    \
            SET##_1l0 = *(const short8v*)(pAl + 131072 + o_);                 \
            SET##_1l1 = *(const short8v*)(pAl + 131072 + o_ + 512);           \
        }                                                                     \
    }

    f32x16 acc00 = 0.0f, acc01 = 0.0f, acc10 = 0.0f, acc11 = 0.0f;

#define MFMA(A_, B_, C_) C_ = __builtin_amdgcn_mfma_f32_32x32x16_bf16(A_, B_, C_, 0, 0, 0)
#define MMKS(SET, BUF_, TS_, KH_)                                             \
    {                                                                         \
        short8v bh0 = BFRAG(BUF_, TS_, 0, KH_, 0);                            \
        short8v bh1 = BFRAG(BUF_, TS_, 0, KH_, 1);                            \
        MFMA(SET##_0h##KH_, bh0, acc00); MFMA(SET##_0h##KH_, bh1, acc01);     \
        MFMA(SET##_1h##KH_, bh0, acc10); MFMA(SET##_1h##KH_, bh1, acc11);     \
        if constexpr (SPLIT) {                                                \
            short8v bl0 = BFRAG(BUF_, TS_, 1, KH_, 0);                        \
            short8v bl1 = BFRAG(BUF_, TS_, 1, KH_, 1);                        \
            MFMA(SET##_0h##KH_, bl0, acc00); MFMA(SET##_0h##KH_, bl1, acc01); \
            MFMA(SET##_1h##KH_, bl0, acc10); MFMA(SET##_1h##KH_, bl1, acc11); \
            MFMA(SET##_0l##KH_, bh0, acc00); MFMA(SET##_0l##KH_, bh1, acc01); \
            MFMA(SET##_1l##KH_, bh0, acc10); MFMA(SET##_1l##KH_, bh1, acc11); \
        }                                                                     \
    }

    // prologue: tiles 0,1 -> buf0; A(0),A(1) -> cA,nA
    LOADB(r, 0)
    LOADB(s, 1)
    LOADA(cA, 0)
    LOADA(nA, 1)
    WRITEB(r, 0, 0)
    WRITEB(s, 0, 1)
    __syncthreads();

#pragma unroll
    for (int tp = 0; tp < 8; ++tp) {
        const int cur = tp & 1, nxt = cur ^ 1;
        const int t = tp * 2;
        // stage next tile-pair's loads early
        if (tp < 7) { LOADB(r, t + 2) LOADB(s, t + 3) }
        // tile t (cur buf, slot 0, cA)
        __builtin_amdgcn_s_setprio(1);
        MMKS(cA, cur, 0, 0)
        MMKS(cA, cur, 0, 1)
        __builtin_amdgcn_s_setprio(0);
        if (tp < 7) { LOADA(cA, t + 2) }
        // tile t+1 (cur buf, slot 1, nA)
        __builtin_amdgcn_s_setprio(1);
        MMKS(nA, cur, 1, 0)
        MMKS(nA, cur, 1, 1)
        __builtin_amdgcn_s_setprio(0);
        if (tp < 7) {
            LOADA(nA, t + 3)
            WRITEB(r, nxt, 0)
            WRITEB(s, nxt, 1)
        }
        __syncthreads();
    }
#undef LOADB
#undef WRITEB
#undef BFRAG
#undef LOADA
#undef MFMA
#undef MMKS

    float* pp = part + (size_t)blockIdx.z * (MB * FF);
    const int rbase = wm * 64 + 4 * (lane >> 5);
    const int c0 = bn0 + wn * 64 + l31;
#pragma unroll
    for (int r = 0; r < 16; ++r) {
        const int row0 = rbase + (r & 3) + 8 * (r >> 2);
        float* rp0 = pp + (size_t)row0 * FF + c0;
        rp0[0]  = acc00[r];
        rp0[32] = acc01[r];
        float* rp1 = rp0 + (size_t)32 * FF;
        rp1[0]  = acc10[r];
        rp1[32] = acc11[r];
    }
}

// ---------------- split-K reduce + epilogue (PACKED bf16 outputs) ----------
// MODE 0: +bias -> packed hi/lo.  MODE 1: +bias -> packed hi/lo + linear f32.
// MODE 3: plain -> linear f32.
template <int MODE>
__global__ __launch_bounds__(256) void reduce_k(
    const float* __restrict__ part, const float* __restrict__ bias,
    unsigned short* __restrict__ hi, unsigned short* __restrict__ lo,
    float* __restrict__ fout)
{
    const size_t idx4 = (size_t)blockIdx.x * 256 + threadIdx.x;
    const size_t base = idx4 * 4;
    float s0 = 0.f, s1 = 0.f, s2 = 0.f, s3 = 0.f;
#pragma unroll
    for (int c = 0; c < 8; ++c) {
        const float4 p = *(const float4*)(part + (size_t)c * (MB * FF) + base);
        s0 += p.x; s1 += p.y; s2 += p.z; s3 += p.w;
    }
    const int col = (int)(base & 4095);
    const int row = (int)(base >> 12);
    if constexpr (MODE == 0 || MODE == 1) {
        s0 += bias[col]; s1 += bias[col + 1]; s2 += bias[col + 2]; s3 += bias[col + 3];
        unsigned short h0 = bf16_rne(s0), h1 = bf16_rne(s1), h2 = bf16_rne(s2), h3 = bf16_rne(s3);
        const size_t po = apack_idx(row, col);
        short4v hv = { (short)h0, (short)h1, (short)h2, (short)h3 };
        *(short4v*)(hi + po) = hv;
        short4v lv = { (short)bf16_rne(s0 - bf16_f(h0)), (short)bf16_rne(s1 - bf16_f(h1)),
                       (short)bf16_rne(s2 - bf16_f(h2)), (short)bf16_rne(s3 - bf16_f(h3)) };
        *(short4v*)(lo + po) = lv;
        if constexpr (MODE == 1) {
            float4 o = { s0, s1, s2, s3 };
            *(float4*)(fout + base) = o;
        }
    } else {
        float4 o = { s0, s1, s2, s3 };
        *(float4*)(fout + base) = o;
    }
}

// ---------------- fused: split-K reduce + cosine scale + softmax +
//                  shrinkage + renorm + entropy -> packed w_hi ----------------
__global__ __launch_bounds__(256) void reduce_softmax(
    const float* __restrict__ part, const float* __restrict__ zn,
    const float* __restrict__ mn, unsigned short* __restrict__ w_hi,
    float* __restrict__ rowent)
{
    constexpr float THRESH = 1.0f / 4096.0f;
    constexpr float EPS = 1e-12f;
    __shared__ float srow[4096];
    __shared__ float red[256];
    const int row = blockIdx.x, tid = threadIdx.x;
    const float zr = zn[row];

    for (int i = tid; i < 1024; i += 256) {
        float s0 = 0.f, s1 = 0.f, s2 = 0.f, s3 = 0.f;
#pragma unroll
        for (int c = 0; c < 8; ++c) {
            const float4 p = *(const float4*)(part + (size_t)c * (MB * FF)
                                              + (size_t)row * FF + i * 4);
            s0 += p.x; s1 += p.y; s2 += p.z; s3 += p.w;
        }
        const float4 mv = *(const float4*)(mn + i * 4);
        float4 o = { s0 / (zr * mv.x), s1 / (zr * mv.y),
                     s2 / (zr * mv.z), s3 / (zr * mv.w) };
        *(float4*)(srow + i * 4) = o;
    }
    __syncthreads();

    float m = -INFINITY;
    for (int i = tid; i < FF; i += 256) m = fmaxf(m, srow[i]);
    m = block_reduce_max(m, red);

    float s = 0.f;
    for (int i = tid; i < FF; i += 256) {
        float e = expf(srow[i] - m);
        srow[i] = e; s += e;
    }
    s = block_reduce_sum(s, red);
    const float inv = 1.0f / s;

    float s2 = 0.f;
    for (int i = tid; i < FF; i += 256) {
        float ww = srow[i] * inv;
        float d = ww - THRESH;
        float w2 = fmaxf(d, 0.f) * ww / (fabsf(d) + EPS);
        srow[i] = w2; s2 += w2;
    }
    __syncthreads();
    s2 = block_reduce_sum(s2, red);
    const float inv2 = 1.0f / fmaxf(s2, EPS);

    float ent = 0.f;
    // 8 elements per thread per iter -> one 16B packed-granule write
    for (int i0 = tid * 8; i0 < FF; i0 += 2048) {
        unsigned short h[8];
#pragma unroll
        for (int j = 0; j < 8; ++j) {
            float w3 = srow[i0 + j] * inv2;
            h[j] = bf16_rne(w3);
            ent -= w3 * logf(w3 + EPS);
        }
        short8v hv = { (short)h[0], (short)h[1], (short)h[2], (short)h[3],
                       (short)h[4], (short)h[5], (short)h[6], (short)h[7] };
        *(short8v*)(w_hi + apack_idx(row, i0)) = hv;
    }
    ent = block_reduce_sum(ent, red);
    if (tid == 0) rowent[row] = ent;
}

__global__ __launch_bounds__(256) void loss_kernel(
    const float* __restrict__ rowent, float* __restrict__ out)
{
    __shared__ float red[256];
    const int tid = threadIdx.x;
    float tot = block_reduce_sum(rowent[tid], red);
    if (tid == 0) out[0] = (tot / 256.0f) * 0.0002f;
}

extern "C" void kernel_launch(void* const* d_in, const int* in_sizes, int n_in,
                              void* d_out, int out_size, void* d_ws, size_t ws_size,
                              hipStream_t stream)
{
    // inputs: x, memory, Wq, bq, Wk, bk, Wv, bv, Wo, bo
    const float* x   = (const float*)d_in[0];
    const float* mem = (const float*)d_in[1];
    const float* Wv  = (const float*)d_in[6];
    const float* bv  = (const float*)d_in[7];
    const float* Wo  = (const float*)d_in[8];
    const float* bo  = (const float*)d_in[9];
    float* out = (float*)d_out;

    char* ws = (char*)d_ws;
    float*          part  = (float*)(ws + 134217728ull);           // 32 MB (8 split-K partials)
    unsigned short* x_hi  = (unsigned short*)(ws + 167772160ull);  // 2 MB (packed)
    unsigned short* x_lo  = (unsigned short*)(ws + 169869312ull);
    unsigned short* v_hi  = (unsigned short*)(ws + 171966464ull);
    unsigned short* v_lo  = (unsigned short*)(ws + 174063616ull);
    unsigned short* o_hi  = (unsigned short*)(ws + 176160768ull);
    unsigned short* o_lo  = (unsigned short*)(ws + 178257920ull);
    float*          o_f32 = (float*)(ws + 180355072ull);           // 4 MB (linear)
    unsigned short* w_hi  = (unsigned short*)(ws + 188743680ull);  // 2 MB (packed)
    float*          zn    = (float*)(ws + 190840832ull);
    float*          mn    = zn + MB;
    float*          rowe  = mn + FF;

    const dim3 blk(256);
    const dim3 blkG(512);
    const dim3 gG(32, 1, 8);               // gemm: N/128, M/256, split-K 8
    const int gR = (MB * FF) / (4 * 256);  // 1024

    // prep: x split (packed); mem row norms (read-only)
    split_plain<<<gR, blk, 0, stream>>>(x, x_hi, x_lo);
    rownorm_kernel<<<FF, blk, 0, stream>>>(mem, mn, FF);

    // v = z @ Wv + bv   (B = raw fp32 Wv [k][n])
    gemm_sk<0, 1><<<gG, blkG, 0, stream>>>(x_hi, x_lo, Wv, part);
    reduce_k<0><<<gR, blk, 0, stream>>>(part, bv, v_hi, v_lo, nullptr);

    // o = v @ Wo + bo
    gemm_sk<0, 1><<<gG, blkG, 0, stream>>>(v_hi, v_lo, Wo, part);
    reduce_k<1><<<gR, blk, 0, stream>>>(part, bo, o_hi, o_lo, o_f32);

    // logits = (o @ mem^T) / (zn x mn)  (B = raw fp32 mem [n][k])
    rownorm_kernel<<<MB, blk, 0, stream>>>(o_f32, zn, FF);
    gemm_sk<1, 1><<<gG, blkG, 0, stream>>>(o_hi, o_lo, mem, part);
    reduce_softmax<<<MB, blk, 0, stream>>>(part, zn, mn, w_hi, rowe);

    // z_hat = w @ mem  (B = raw fp32 mem [k][n], round-only, plain bf16)
    gemm_sk<0, 0><<<gG, blkG, 0, stream>>>(w_hi, nullptr, mem, part);
    reduce_k<3><<<gR, blk, 0, stream>>>(part, nullptr, nullptr, nullptr, out);

    loss_kernel<<<1, blk, 0, stream>>>(rowe, out + (size_t)MB * FF);
}

// Round 16
// 179.979 us; speedup vs baseline: 1.0451x; 1.0451x over previous
//
#include <hip/hip_runtime.h>
#include <math.h>

// MultiHeadAttentionMemory: B=256, F=4096, M=4096 memories.
// seq_len==1 => attention==identity => o = (z@Wv+bv)@Wo+bo  (Wq/Wk dead).
// Split-bf16 (bf16x3: ah*bh + ah*bl + al*bh) MFMA for the 3 precision-
// sensitive GEMMs; plain bf16 MFMA for z_hat = w@mem.
// FINAL = R10 (best measured: 181 us): A operand stored PACKED in
// MFMA-fragment order (wave-contiguous 1KB frag loads), coalesced fp32 B
// staging fused with transpose/split, BM=256/BN=128 2-phase LDS loop,
// grid (32,1,8) split-K 8, separate reduce kernels.
#define MB 256
#define FF 4096

typedef __attribute__((ext_vector_type(8))) short short8v;
typedef __attribute__((ext_vector_type(4))) short short4v;
typedef __attribute__((ext_vector_type(16))) float f32x16;

__device__ __forceinline__ unsigned short bf16_rne(float f) {
    unsigned u = __builtin_bit_cast(unsigned, f);
    u += 0x7fffu + ((u >> 16) & 1u);
    return (unsigned short)(u >> 16);
}
__device__ __forceinline__ float bf16_f(unsigned short h) {
    unsigned u = ((unsigned)h) << 16;
    return __builtin_bit_cast(float, u);
}
// packed-A element index (in shorts); m in [0,256), k in [0,4096)
__device__ __forceinline__ size_t apack_idx(int m, int k) {
    return ((size_t)(m >> 5) << 17) + ((size_t)(k >> 3) << 8)
         + ((m & 31) << 3) + (k & 7);
}

// ---------------- reductions ----------------
__device__ __forceinline__ float block_reduce_sum(float v, float* red) {
    const int tid = threadIdx.x;
    red[tid] = v; __syncthreads();
    for (int s = 128; s > 0; s >>= 1) {
        if (tid < s) red[tid] += red[tid + s];
        __syncthreads();
    }
    float r = red[0]; __syncthreads();
    return r;
}
__device__ __forceinline__ float block_reduce_max(float v, float* red) {
    const int tid = threadIdx.x;
    red[tid] = v; __syncthreads();
    for (int s = 128; s > 0; s >>= 1) {
        if (tid < s) red[tid] = fmaxf(red[tid], red[tid + s]);
        __syncthreads();
    }
    float r = red[0]; __syncthreads();
    return r;
}

// dst[row] = max(||src[row,:]||, 1e-8)
__global__ __launch_bounds__(256) void rownorm_kernel(
    const float* __restrict__ src, float* __restrict__ dst, int ncols)
{
    __shared__ float red[256];
    const int row = blockIdx.x, tid = threadIdx.x;
    const float4* p = (const float4*)(src + (size_t)row * ncols);
    float s = 0.f;
    for (int i = tid; i < ncols / 4; i += 256) {
        float4 v = p[i];
        s += v.x * v.x + v.y * v.y + v.z * v.z + v.w * v.w;
    }
    float tot = block_reduce_sum(s, red);
    if (tid == 0) dst[row] = fmaxf(sqrtf(tot), 1e-8f);
}

// ---------------- fp32 -> bf16 hi/lo split, PACKED output ----------------
__global__ __launch_bounds__(256) void split_plain(
    const float* __restrict__ src, unsigned short* __restrict__ hi,
    unsigned short* __restrict__ lo)
{
    const size_t i4 = (size_t)blockIdx.x * 256 + threadIdx.x;
    const size_t base = i4 * 4;
    const int m = (int)(base >> 12), k = (int)(base & 4095);
    const float4 v = *(const float4*)(src + base);
    unsigned short h0 = bf16_rne(v.x), h1 = bf16_rne(v.y), h2 = bf16_rne(v.z), h3 = bf16_rne(v.w);
    const size_t po = apack_idx(m, k);   // k aligned to 4 -> 4 contiguous shorts
    short4v hv = { (short)h0, (short)h1, (short)h2, (short)h3 };
    *(short4v*)(hi + po) = hv;
    short4v lv = { (short)bf16_rne(v.x - bf16_f(h0)), (short)bf16_rne(v.y - bf16_f(h1)),
                   (short)bf16_rne(v.z - bf16_f(h2)), (short)bf16_rne(v.w - bf16_f(h3)) };
    *(short4v*)(lo + po) = lv;
}

// ---------------- MFMA GEMM, split-K ----------------
// C[256][4096](->part) = A[256][4096] @ B, BM=256, BN=128, BK=32,
// K-chunk 512 (16 tiles). Block = 512 threads = 8 waves (4m x 2n),
// wave tile 64x64. grid (32, 1, 8) = 256 blocks.
// A: PACKED bf16 planes, register-direct, coalesced frag loads, 1-ahead.
// BSRC 0: B raw fp32 [k][n] (weights; zhat's mem) - coalesced scalar loads.
// BSRC 1: B raw fp32 [n][k] (logits' mem rows) - 32B/lane contiguous loads.
// B split/rounded in-VALU -> blocked LDS granule (k8*128+n)*16B per plane.
template <int BSRC, int SPLIT>
__global__ __launch_bounds__(512, 2) void gemm_sk(
    const unsigned short* __restrict__ Ah, const unsigned short* __restrict__ Al,
    const float* __restrict__ B, float* __restrict__ part)
{
    constexpr int PLANES = SPLIT ? 2 : 1;
    constexpr int BUFBYTES = PLANES * 8192;
    __shared__ char Bs[2 * BUFBYTES];

    const int tid = threadIdx.x;
    const int lane = tid & 63, w = tid >> 6;
    const int wm = w >> 1, wn = w & 1;
    const int bn0 = blockIdx.x * 128;
    const int k0 = blockIdx.z * 512;
    const int l31 = lane & 31;

    // ---- staging source + LDS granule slot
    const float* bsrc;
    int gslot;
    if constexpr (BSRC == 0) {
        const int tk8 = tid >> 7, tn = tid & 127;       // k8 0..3, n 0..127
        bsrc = B + (size_t)(k0 + tk8 * 8) * FF + bn0 + tn;
        gslot = tid;                                     // = tk8*128 + tn
    } else {
        const int tn = tid >> 2, tk8 = tid & 3;          // n 0..127, k8 0..3
        bsrc = B + (size_t)(bn0 + tn) * FF + k0 + tk8 * 8;
        gslot = tk8 * 128 + tn;
    }

    float rB0, rB1, rB2, rB3, rB4, rB5, rB6, rB7;
    float sB0, sB1, sB2, sB3, sB4, sB5, sB6, sB7;

#define LOADB(S, T_)                                                          \
    {                                                                         \
        if constexpr (BSRC == 0) {                                            \
            const float* p_ = bsrc + (size_t)(T_) * 32 * FF;                  \
            S##B0 = p_[0 * FF]; S##B1 = p_[1 * FF];                           \
            S##B2 = p_[2 * FF]; S##B3 = p_[3 * FF];                           \
            S##B4 = p_[4 * FF]; S##B5 = p_[5 * FF];                           \
            S##B6 = p_[6 * FF]; S##B7 = p_[7 * FF];                           \
        } else {                                                              \
            const float* p_ = bsrc + (T_) * 32;                               \
            const float4 f0_ = *(const float4*)p_;                            \
            const float4 f1_ = *(const float4*)(p_ + 4);                      \
            S##B0 = f0_.x; S##B1 = f0_.y; S##B2 = f0_.z; S##B3 = f0_.w;       \
            S##B4 = f1_.x; S##B5 = f1_.y; S##B6 = f1_.z; S##B7 = f1_.w;       \
        }                                                                     \
    }

#define WRITEB(S, BUF_)                                                       \
    {                                                                         \
        unsigned short h0_ = bf16_rne(S##B0), h1_ = bf16_rne(S##B1),          \
                       h2_ = bf16_rne(S##B2), h3_ = bf16_rne(S##B3),          \
                       h4_ = bf16_rne(S##B4), h5_ = bf16_rne(S##B5),          \
                       h6_ = bf16_rne(S##B6), h7_ = bf16_rne(S##B7);          \
        short8v hv_ = { (short)h0_, (short)h1_, (short)h2_, (short)h3_,       \
                        (short)h4_, (short)h5_, (short)h6_, (short)h7_ };     \
        *(short8v*)(Bs + (BUF_) * BUFBYTES + gslot * 16) = hv_;               \
        if constexpr (SPLIT) {                                                \
            short8v lv_ = { (short)bf16_rne(S##B0 - bf16_f(h0_)),             \
                            (short)bf16_rne(S##B1 - bf16_f(h1_)),             \
                            (short)bf16_rne(S##B2 - bf16_f(h2_)),             \
                            (short)bf16_rne(S##B3 - bf16_f(h3_)),             \
                            (short)bf16_rne(S##B4 - bf16_f(h4_)),             \
                            (short)bf16_rne(S##B5 - bf16_f(h5_)),             \
                            (short)bf16_rne(S##B6 - bf16_f(h6_)),             \
                            (short)bf16_rne(S##B7 - bf16_f(h7_)) };           \
            *(short8v*)(Bs + (BUF_) * BUFBYTES + 8192 + gslot * 16) = lv_;    \
        }                                                                     \
    }

    // ---- B fragment reads: byte = ((KH*2+(lane>>5))*128 + wn*64 + ns*32 + l31)*16
    const char* const fragbase =
        (const char*)Bs + (((lane >> 5) * 128) + wn * 64 + l31) * 16;
#define BFRAG(BUF_, P_, KH_, NS_)                                             \
    (*(const short8v*)(fragbase + (BUF_) * BUFBYTES + (P_) * 8192 + (KH_) * 4096 + (NS_) * 512))

    // ---- A pointers (packed planes, coalesced): wave rows wm*64 .. +63
    const size_t abase = ((size_t)(wm * 2) << 17) + ((size_t)blockIdx.z << 14)
                       + ((lane >> 5) << 8) + (l31 << 3);
    const unsigned short* pAh = Ah + abase;
    const unsigned short* pAl = SPLIT ? (Al + abase) : pAh;

    short8v cA_0h0, cA_0h1, cA_1h0, cA_1h1, cA_0l0, cA_0l1, cA_1l0, cA_1l1;
    short8v nA_0h0, nA_0h1, nA_1h0, nA_1h1, nA_0l0, nA_0l1, nA_1l0, nA_1l1;

    // A frag offsets (shorts): s*131072 + t*1024 + h*512
#define LOADA(SET, T_)                                                        \
    {                                                                         \
        const int o_ = (T_) * 1024;                                           \
        SET##_0h0 = *(const short8v*)(pAh + o_);                              \
        SET##_0h1 = *(const short8v*)(pAh + o_ + 512);                        \
        SET##_1h0 = *(const short8v*)(pAh + 131072 + o_);                     \
        SET##_1h1 = *(const short8v*)(pAh + 131072 + o_ + 512);               \
        if constexpr (SPLIT) {                                                \
            SET##_0l0 = *(const short8v*)(pAl + o_);                          \
            SET##_0l1 = *(const short8v*)(pAl + o_ + 512);                    \
            SET##_1l0 = *(const short8v*)(pAl + 131072 + o_);                 \
            SET##_1l1 = *(const short8v*)(pAl + 131072 + o_ + 512);           \
        }                                                                     \
    }

    f32x16 acc00 = 0.0f, acc01 = 0.0f, acc10 = 0.0f, acc11 = 0.0f;

#define MFMA(A_, B_, C_) C_ = __builtin_amdgcn_mfma_f32_32x32x16_bf16(A_, B_, C_, 0, 0, 0)
#define MMKS(SET, BUF_, KH_)                                                  \
    {                                                                         \
        short8v bh0 = BFRAG(BUF_, 0, KH_, 0);                                 \
        short8v bh1 = BFRAG(BUF_, 0, KH_, 1);                                 \
        MFMA(SET##_0h##KH_, bh0, acc00); MFMA(SET##_0h##KH_, bh1, acc01);     \
        MFMA(SET##_1h##KH_, bh0, acc10); MFMA(SET##_1h##KH_, bh1, acc11);     \
        if constexpr (SPLIT) {                                                \
            short8v bl0 = BFRAG(BUF_, 1, KH_, 0);                             \
            short8v bl1 = BFRAG(BUF_, 1, KH_, 1);                             \
            MFMA(SET##_0h##KH_, bl0, acc00); MFMA(SET##_0h##KH_, bl1, acc01); \
            MFMA(SET##_1h##KH_, bl0, acc10); MFMA(SET##_1h##KH_, bl1, acc11); \
            MFMA(SET##_0l##KH_, bh0, acc00); MFMA(SET##_0l##KH_, bh1, acc01); \
            MFMA(SET##_1l##KH_, bh0, acc10); MFMA(SET##_1l##KH_, bh1, acc11); \
        }                                                                     \
    }

    // prologue: tile 0 -> buf0, A(0) -> cA
    LOADB(r, 0)
    LOADA(cA, 0)
    WRITEB(r, 0)
    __syncthreads();

#pragma unroll
    for (int tp = 0; tp < 8; ++tp) {
        const int t = tp * 2;
        // even tile t (buf0, cA); stage t+1 -> buf1, prefetch A(t+1)
        LOADB(s, t + 1)
        LOADA(nA, t + 1)
        __builtin_amdgcn_s_setprio(1);
        MMKS(cA, 0, 0)
        MMKS(cA, 0, 1)
        __builtin_amdgcn_s_setprio(0);
        WRITEB(s, 1)
        __syncthreads();
        // odd tile t+1 (buf1, nA); stage t+2 -> buf0, prefetch A(t+2)
        if (tp < 7) { LOADB(r, t + 2) LOADA(cA, t + 2) }
        __builtin_amdgcn_s_setprio(1);
        MMKS(nA, 1, 0)
        MMKS(nA, 1, 1)
        __builtin_amdgcn_s_setprio(0);
        if (tp < 7) { WRITEB(r, 0) }
        __syncthreads();
    }
#undef LOADB
#undef WRITEB
#undef BFRAG
#undef LOADA
#undef MFMA
#undef MMKS

    float* pp = part + (size_t)blockIdx.z * (MB * FF);
    const int rbase = wm * 64 + 4 * (lane >> 5);
    const int c0 = bn0 + wn * 64 + l31;
#pragma unroll
    for (int r = 0; r < 16; ++r) {
        const int row0 = rbase + (r & 3) + 8 * (r >> 2);
        float* rp0 = pp + (size_t)row0 * FF + c0;
        rp0[0]  = acc00[r];
        rp0[32] = acc01[r];
        float* rp1 = rp0 + (size_t)32 * FF;
        rp1[0]  = acc10[r];
        rp1[32] = acc11[r];
    }
}

// ---------------- split-K reduce + epilogue (PACKED bf16 outputs) ----------
// MODE 0: +bias -> packed hi/lo.  MODE 1: +bias -> packed hi/lo + linear f32.
// MODE 3: plain -> linear f32.
template <int MODE>
__global__ __launch_bounds__(256) void reduce_k(
    const float* __restrict__ part, const float* __restrict__ bias,
    unsigned short* __restrict__ hi, unsigned short* __restrict__ lo,
    float* __restrict__ fout)
{
    const size_t idx4 = (size_t)blockIdx.x * 256 + threadIdx.x;
    const size_t base = idx4 * 4;
    float s0 = 0.f, s1 = 0.f, s2 = 0.f, s3 = 0.f;
#pragma unroll
    for (int c = 0; c < 8; ++c) {
        const float4 p = *(const float4*)(part + (size_t)c * (MB * FF) + base);
        s0 += p.x; s1 += p.y; s2 += p.z; s3 += p.w;
    }
    const int col = (int)(base & 4095);
    const int row = (int)(base >> 12);
    if constexpr (MODE == 0 || MODE == 1) {
        s0 += bias[col]; s1 += bias[col + 1]; s2 += bias[col + 2]; s3 += bias[col + 3];
        unsigned short h0 = bf16_rne(s0), h1 = bf16_rne(s1), h2 = bf16_rne(s2), h3 = bf16_rne(s3);
        const size_t po = apack_idx(row, col);
        short4v hv = { (short)h0, (short)h1, (short)h2, (short)h3 };
        *(short4v*)(hi + po) = hv;
        short4v lv = { (short)bf16_rne(s0 - bf16_f(h0)), (short)bf16_rne(s1 - bf16_f(h1)),
                       (short)bf16_rne(s2 - bf16_f(h2)), (short)bf16_rne(s3 - bf16_f(h3)) };
        *(short4v*)(lo + po) = lv;
        if constexpr (MODE == 1) {
            float4 o = { s0, s1, s2, s3 };
            *(float4*)(fout + base) = o;
        }
    } else {
        float4 o = { s0, s1, s2, s3 };
        *(float4*)(fout + base) = o;
    }
}

// ---------------- fused: split-K reduce + cosine scale + softmax +
//                  shrinkage + renorm + entropy -> packed w_hi ----------------
__global__ __launch_bounds__(256) void reduce_softmax(
    const float* __restrict__ part, const float* __restrict__ zn,
    const float* __restrict__ mn, unsigned short* __restrict__ w_hi,
    float* __restrict__ rowent)
{
    constexpr float THRESH = 1.0f / 4096.0f;
    constexpr float EPS = 1e-12f;
    __shared__ float srow[4096];
    __shared__ float red[256];
    const int row = blockIdx.x, tid = threadIdx.x;
    const float zr = zn[row];

    for (int i = tid; i < 1024; i += 256) {
        float s0 = 0.f, s1 = 0.f, s2 = 0.f, s3 = 0.f;
#pragma unroll
        for (int c = 0; c < 8; ++c) {
            const float4 p = *(const float4*)(part + (size_t)c * (MB * FF)
                                              + (size_t)row * FF + i * 4);
            s0 += p.x; s1 += p.y; s2 += p.z; s3 += p.w;
        }
        const float4 mv = *(const float4*)(mn + i * 4);
        float4 o = { s0 / (zr * mv.x), s1 / (zr * mv.y),
                     s2 / (zr * mv.z), s3 / (zr * mv.w) };
        *(float4*)(srow + i * 4) = o;
    }
    __syncthreads();

    float m = -INFINITY;
    for (int i = tid; i < FF; i += 256) m = fmaxf(m, srow[i]);
    m = block_reduce_max(m, red);

    float s = 0.f;
    for (int i = tid; i < FF; i += 256) {
        float e = expf(srow[i] - m);
        srow[i] = e; s += e;
    }
    s = block_reduce_sum(s, red);
    const float inv = 1.0f / s;

    float s2 = 0.f;
    for (int i = tid; i < FF; i += 256) {
        float ww = srow[i] * inv;
        float d = ww - THRESH;
        float w2 = fmaxf(d, 0.f) * ww / (fabsf(d) + EPS);
        srow[i] = w2; s2 += w2;
    }
    __syncthreads();
    s2 = block_reduce_sum(s2, red);
    const float inv2 = 1.0f / fmaxf(s2, EPS);

    float ent = 0.f;
    // 8 elements per thread per iter -> one 16B packed-granule write
    for (int i0 = tid * 8; i0 < FF; i0 += 2048) {
        unsigned short h[8];
#pragma unroll
        for (int j = 0; j < 8; ++j) {
            float w3 = srow[i0 + j] * inv2;
            h[j] = bf16_rne(w3);
            ent -= w3 * logf(w3 + EPS);
        }
        short8v hv = { (short)h[0], (short)h[1], (short)h[2], (short)h[3],
                       (short)h[4], (short)h[5], (short)h[6], (short)h[7] };
        *(short8v*)(w_hi + apack_idx(row, i0)) = hv;
    }
    ent = block_reduce_sum(ent, red);
    if (tid == 0) rowent[row] = ent;
}

__global__ __launch_bounds__(256) void loss_kernel(
    const float* __restrict__ rowent, float* __restrict__ out)
{
    __shared__ float red[256];
    const int tid = threadIdx.x;
    float tot = block_reduce_sum(rowent[tid], red);
    if (tid == 0) out[0] = (tot / 256.0f) * 0.0002f;
}

extern "C" void kernel_launch(void* const* d_in, const int* in_sizes, int n_in,
                              void* d_out, int out_size, void* d_ws, size_t ws_size,
                              hipStream_t stream)
{
    // inputs: x, memory, Wq, bq, Wk, bk, Wv, bv, Wo, bo
    const float* x   = (const float*)d_in[0];
    const float* mem = (const float*)d_in[1];
    const float* Wv  = (const float*)d_in[6];
    const float* bv  = (const float*)d_in[7];
    const float* Wo  = (const float*)d_in[8];
    const float* bo  = (const float*)d_in[9];
    float* out = (float*)d_out;

    char* ws = (char*)d_ws;
    float*          part  = (float*)(ws + 134217728ull);           // 32 MB (8 split-K partials)
    unsigned short* x_hi  = (unsigned short*)(ws + 167772160ull);  // 2 MB (packed)
    unsigned short* x_lo  = (unsigned short*)(ws + 169869312ull);
    unsigned short* v_hi  = (unsigned short*)(ws + 171966464ull);
    unsigned short* v_lo  = (unsigned short*)(ws + 174063616ull);
    unsigned short* o_hi  = (unsigned short*)(ws + 176160768ull);
    unsigned short* o_lo  = (unsigned short*)(ws + 178257920ull);
    float*          o_f32 = (float*)(ws + 180355072ull);           // 4 MB (linear)
    unsigned short* w_hi  = (unsigned short*)(ws + 188743680ull);  // 2 MB (packed)
    float*          zn    = (float*)(ws + 190840832ull);
    float*          mn    = zn + MB;
    float*          rowe  = mn + FF;

    const dim3 blk(256);
    const dim3 blkG(512);
    const dim3 gG(32, 1, 8);               // gemm: N/128, M/256, split-K 8
    const int gR = (MB * FF) / (4 * 256);  // 1024

    // prep: x split (packed); mem row norms (read-only)
    split_plain<<<gR, blk, 0, stream>>>(x, x_hi, x_lo);
    rownorm_kernel<<<FF, blk, 0, stream>>>(mem, mn, FF);

    // v = z @ Wv + bv   (B = raw fp32 Wv [k][n])
    gemm_sk<0, 1><<<gG, blkG, 0, stream>>>(x_hi, x_lo, Wv, part);
    reduce_k<0><<<gR, blk, 0, stream>>>(part, bv, v_hi, v_lo, nullptr);

    // o = v @ Wo + bo
    gemm_sk<0, 1><<<gG, blkG, 0, stream>>>(v_hi, v_lo, Wo, part);
    reduce_k<1><<<gR, blk, 0, stream>>>(part, bo, o_hi, o_lo, o_f32);

    // logits = (o @ mem^T) / (zn x mn)  (B = raw fp32 mem [n][k])
    rownorm_kernel<<<MB, blk, 0, stream>>>(o_f32, zn, FF);
    gemm_sk<1, 1><<<gG, blkG, 0, stream>>>(o_hi, o_lo, mem, part);
    reduce_softmax<<<MB, blk, 0, stream>>>(part, zn, mn, w_hi, rowe);

    // z_hat = w @ mem  (B = raw fp32 mem [k][n], round-only, plain bf16)
    gemm_sk<0, 0><<<gG, blkG, 0, stream>>>(w_hi, nullptr, mem, part);
    reduce_k<3><<<gR, blk, 0, stream>>>(part, nullptr, nullptr, nullptr, out);

    loss_kernel<<<1, blk, 0, stream>>>(rowe, out + (size_t)MB * FF);
}